// Round 1
// baseline (5001.339 us; speedup 1.0000x reference)
//
#include <hip/hip_runtime.h>
#include <hip/hip_bf16.h>

#define DEVI __device__ __forceinline__

#define ASR_DIM 1024
#define VOCAB   32000
#define LLM_DIM 4096
#define MROWS   8192   // 4*2048

typedef __bf16 bf16x8 __attribute__((ext_vector_type(8)));
typedef float floatx4 __attribute__((ext_vector_type(4)));
typedef unsigned short ushortx8 __attribute__((ext_vector_type(8)));

DEVI unsigned short f2bf(float f) {
    union { __hip_bfloat16 h; unsigned short u; } cv;
    cv.h = __float2bfloat16(f);
    return cv.u;
}
DEVI float bf2f(unsigned short u) {
    return __builtin_bit_cast(float, (unsigned int)u << 16);
}

// async global->LDS, 16B per lane. LDS dest: wave-uniform base + lane*16.
DEVI void async16(const unsigned short* g, unsigned short* l) {
    __builtin_amdgcn_global_load_lds(
        (const __attribute__((address_space(1))) unsigned int*)g,
        (__attribute__((address_space(3))) unsigned int*)l,
        16, 0, 0);
}

// ---------------- fp32 -> bf16 convert (8 elems/thread) ----------------
__global__ __launch_bounds__(256) void convert_kernel(
    const float* __restrict__ src, unsigned short* __restrict__ dst, int n8) {
    int i = blockIdx.x * blockDim.x + threadIdx.x;
    if (i >= n8) return;
    const float4* s4 = (const float4*)src;
    float4 a = s4[2 * i], b = s4[2 * i + 1];
    ushortx8 o;
    o[0] = f2bf(a.x); o[1] = f2bf(a.y); o[2] = f2bf(a.z); o[3] = f2bf(a.w);
    o[4] = f2bf(b.x); o[5] = f2bf(b.y); o[6] = f2bf(b.z); o[7] = f2bf(b.w);
    ((ushortx8*)dst)[i] = o;
}

// ---------------- fp32 [R][C] -> bf16 [C][R] transpose ----------------
// 64x64 tiles, 256 threads. grid = (C/64, R/64)
__global__ __launch_bounds__(256) void transpose_convert_kernel(
    const float* __restrict__ src, unsigned short* __restrict__ dst, int R, int C) {
    __shared__ float tile[64][65];
    const int tid = threadIdx.x;
    const int rb = blockIdx.y * 64, cb = blockIdx.x * 64;
#pragma unroll
    for (int i = 0; i < 4; ++i) {
        int lin = tid + i * 256;              // 0..1023 float4s
        int r = lin >> 4, c4 = (lin & 15) << 2;
        float4 v = *(const float4*)(src + (size_t)(rb + r) * C + cb + c4);
        tile[r][c4] = v.x; tile[r][c4 + 1] = v.y; tile[r][c4 + 2] = v.z; tile[r][c4 + 3] = v.w;
    }
    __syncthreads();
#pragma unroll
    for (int i = 0; i < 8; ++i) {
        int lin = tid + i * 256;              // 0..2047 ushort2s
        int oc = lin >> 5, r2 = (lin & 31) << 1;
        ushort2 o;
        o.x = f2bf(tile[r2][oc]);
        o.y = f2bf(tile[r2 + 1][oc]);
        *(ushort2*)(dst + (size_t)(cb + oc) * R + rb + r2) = o;
    }
}

// ---------------- bf16 GEMM, B^T input (both A and B K-contiguous) ----------------
// C[M,N] = A[M,K] * B[N,K]^T (+bias). 128x128 tile, BK=32, 256 thr (4 waves),
// each wave 64x64 via 4x4 of mfma_f32_16x16x32_bf16.
// HAS_BIAS=1: out bf16 with fp32 bias add; HAS_BIAS=0: out fp32.
template <int HAS_BIAS>
__global__ __launch_bounds__(256) void gemm_bt_kernel(
    const unsigned short* __restrict__ A, const unsigned short* __restrict__ B,
    const float* __restrict__ bias, void* __restrict__ Cout, int M, int N, int K) {
    __shared__ unsigned short lds_a[128 * 32];
    __shared__ unsigned short lds_b[128 * 32];
    const int tid  = threadIdx.x;
    const int lane = tid & 63;
    const int w    = tid >> 6;
    const size_t tileM = (size_t)blockIdx.y * 128;
    const size_t tileN = (size_t)blockIdx.x * 128;
    const int waveM = (w >> 1) * 64;
    const int waveN = (w & 1) * 64;

    floatx4 acc[4][4] = {};

    // staging: wave w covers tile rows [w*32, w*32+32), 2 insts x 16 rows
    const int srow0  = w * 32 + (lane >> 2);
    const int schunk = (lane & 3) * 8;
    const unsigned short* gA0 = A + (tileM + srow0) * K + schunk;
    const unsigned short* gA1 = gA0 + (size_t)16 * K;
    const unsigned short* gB0 = B + (tileN + srow0) * K + schunk;
    const unsigned short* gB1 = gB0 + (size_t)16 * K;
    unsigned short* lA0 = lds_a + (w * 32) * 32;
    unsigned short* lA1 = lA0 + 16 * 32;
    unsigned short* lB0 = lds_b + (w * 32) * 32;
    unsigned short* lB1 = lB0 + 16 * 32;

    const int fr = lane & 15;
    const int fk = (lane >> 4) * 8;

    for (int k0 = 0; k0 < K; k0 += 32) {
        async16(gA0 + k0, lA0);
        async16(gA1 + k0, lA1);
        async16(gB0 + k0, lB0);
        async16(gB1 + k0, lB1);
        __syncthreads();   // drains vmcnt -> LDS tiles ready

        bf16x8 af[4], bfr[4];
#pragma unroll
        for (int mi = 0; mi < 4; ++mi)
            af[mi] = *(const bf16x8*)(lds_a + (waveM + mi * 16 + fr) * 32 + fk);
#pragma unroll
        for (int ni = 0; ni < 4; ++ni)
            bfr[ni] = *(const bf16x8*)(lds_b + (waveN + ni * 16 + fr) * 32 + fk);
#pragma unroll
        for (int mi = 0; mi < 4; ++mi)
#pragma unroll
            for (int ni = 0; ni < 4; ++ni)
                acc[mi][ni] = __builtin_amdgcn_mfma_f32_16x16x32_bf16(
                    af[mi], bfr[ni], acc[mi][ni], 0, 0, 0);
        __syncthreads();   // protect LDS before next stage
    }

    // epilogue: C/D layout col=lane&15, row=(lane>>4)*4+reg
    const int erow = waveM + ((lane >> 4) << 2);
    const int ecol = waveN + (lane & 15);
    if (HAS_BIAS) {
        unsigned short* C = (unsigned short*)Cout;
        float bv[4];
#pragma unroll
        for (int ni = 0; ni < 4; ++ni) bv[ni] = bias[tileN + ecol + ni * 16];
#pragma unroll
        for (int mi = 0; mi < 4; ++mi)
#pragma unroll
            for (int r = 0; r < 4; ++r) {
                size_t base = (tileM + erow + mi * 16 + r) * (size_t)N + tileN + ecol;
#pragma unroll
                for (int ni = 0; ni < 4; ++ni)
                    C[base + ni * 16] = f2bf(acc[mi][ni][r] + bv[ni]);
            }
    } else {
        float* C = (float*)Cout;
#pragma unroll
        for (int mi = 0; mi < 4; ++mi)
#pragma unroll
            for (int r = 0; r < 4; ++r) {
                size_t base = (tileM + erow + mi * 16 + r) * (size_t)N + tileN + ecol;
#pragma unroll
                for (int ni = 0; ni < 4; ++ni)
                    C[base + ni * 16] = acc[mi][ni][r];
            }
    }
}

// ---------------- in-place row softmax over bf16 logits ----------------
// one block (256 thr) per row; 3 passes, row (64KB) stays L2-hot.
__global__ __launch_bounds__(256) void softmax_kernel(
    unsigned short* __restrict__ logits, int N) {
    const int row = blockIdx.x;
    unsigned short* p = logits + (size_t)row * N;
    const int tid = threadIdx.x;
    const int n8 = N >> 3;
    __shared__ float red[8];

    float mx = -3.0e38f;
    for (int i = tid; i < n8; i += 256) {
        ushortx8 v = ((const ushortx8*)p)[i];
#pragma unroll
        for (int j = 0; j < 8; ++j) mx = fmaxf(mx, bf2f(v[j]));
    }
#pragma unroll
    for (int off = 32; off > 0; off >>= 1) mx = fmaxf(mx, __shfl_xor(mx, off));
    if ((tid & 63) == 0) red[tid >> 6] = mx;
    __syncthreads();
    mx = fmaxf(fmaxf(red[0], red[1]), fmaxf(red[2], red[3]));

    float s = 0.f;
    for (int i = tid; i < n8; i += 256) {
        ushortx8 v = ((const ushortx8*)p)[i];
#pragma unroll
        for (int j = 0; j < 8; ++j) s += __expf(bf2f(v[j]) - mx);
    }
#pragma unroll
    for (int off = 32; off > 0; off >>= 1) s += __shfl_xor(s, off);
    if ((tid & 63) == 0) red[4 + (tid >> 6)] = s;
    __syncthreads();
    const float inv = 1.0f / (red[4] + red[5] + red[6] + red[7]);

    for (int i = tid; i < n8; i += 256) {
        ushortx8 v = ((const ushortx8*)p)[i];
        ushortx8 o;
#pragma unroll
        for (int j = 0; j < 8; ++j) o[j] = f2bf(__expf(bf2f(v[j]) - mx) * inv);
        ((ushortx8*)p)[i] = o;
    }
}

extern "C" void kernel_launch(void* const* d_in, const int* in_sizes, int n_in,
                              void* d_out, int out_size, void* d_ws, size_t ws_size,
                              hipStream_t stream) {
    const float* asr   = (const float*)d_in[0];   // [4,2048,1024]
    const float* projw = (const float*)d_in[1];   // [32000,1024]
    const float* projb = (const float*)d_in[2];   // [32000]
    const float* embw  = (const float*)d_in[3];   // [32000,4096]

    // workspace layout (bf16 elems): asr | proj_w | embed_w^T | logits/probs
    unsigned short* ws      = (unsigned short*)d_ws;
    unsigned short* asr_bf  = ws;
    unsigned short* proj_bf = asr_bf + (size_t)MROWS * ASR_DIM;     //  16.8 MB
    unsigned short* et_bf   = proj_bf + (size_t)VOCAB * ASR_DIM;    //  65.5 MB
    unsigned short* logits  = et_bf + (size_t)LLM_DIM * VOCAB;      // 262.1 MB
    //                                                   logits:      524.3 MB

    // 1) converts
    convert_kernel<<<(MROWS * ASR_DIM / 8) / 256, 256, 0, stream>>>(
        asr, asr_bf, MROWS * ASR_DIM / 8);
    convert_kernel<<<(VOCAB * ASR_DIM / 8) / 256, 256, 0, stream>>>(
        projw, proj_bf, VOCAB * ASR_DIM / 8);
    transpose_convert_kernel<<<dim3(LLM_DIM / 64, VOCAB / 64), 256, 0, stream>>>(
        embw, et_bf, VOCAB, LLM_DIM);

    // 2) GEMM1: logits[M,V] = asr[M,K] * proj_w[V,K]^T + bias  (bf16 out)
    gemm_bt_kernel<1><<<dim3(VOCAB / 128, MROWS / 128), 256, 0, stream>>>(
        asr_bf, proj_bf, projb, (void*)logits, MROWS, VOCAB, ASR_DIM);

    // 3) softmax rows, in place
    softmax_kernel<<<MROWS, 256, 0, stream>>>(logits, VOCAB);

    // 4) GEMM2: out[M,E] = probs[M,V] * (E^T)[E,V]^T  (fp32 out)
    gemm_bt_kernel<0><<<dim3(LLM_DIM / 128, MROWS / 128), 256, 0, stream>>>(
        logits, et_bf, nullptr, d_out, MROWS, LLM_DIM, VOCAB);
}